// Round 3
// baseline (632.785 us; speedup 1.0000x reference)
//
#include <hip/hip_runtime.h>
#include <hip/hip_bf16.h>
#include <math.h>

// ---------------- problem constants ----------------
#define OC     256
#define IC     128
#define HW     56
#define NB     64
#define KK     1152          // IC*9
#define HP     58            // padded spatial
#define PIX    (HW*HW)       // 3136
#define XPAD_ELEMS ((long)NB*HP*HP*IC)   // 27,557,888
#define A_ELEMS    (OC*KK)               // 294,912

typedef __attribute__((ext_vector_type(8))) short          bf16x8;
typedef __attribute__((ext_vector_type(8))) unsigned short u16x8;
typedef __attribute__((ext_vector_type(4))) float          f32x4;

__device__ __forceinline__ void async_load16(const void* g, void* l) {
    __builtin_amdgcn_global_load_lds(
        (const __attribute__((address_space(1))) void*)g,
        (__attribute__((address_space(3))) void*)l, 16, 0, 0);
}

// bf16 RNE convert
__device__ __forceinline__ unsigned short f2bf(float f) {
    unsigned int u = __float_as_uint(f);
    return (unsigned short)((u + 0x7fffu + ((u >> 16) & 1u)) >> 16);
}
__device__ __forceinline__ float bf2f(unsigned short b) {
    return __uint_as_float(((unsigned int)b) << 16);
}

// XOR-swizzled LDS element offset (2-way bank aliasing only — free, m136)
__device__ __forceinline__ int lds_off(int row, int q) {
    return row * 32 + (((q ^ (row >> 1)) & 3) << 3);
}

// ---------------- kernel 1: weights + BN constants ----------------
__global__ __launch_bounds__(256) void prep_weights(
        const float* __restrict__ phase, const float* __restrict__ gamma,
        const float* __restrict__ beta,  const float* __restrict__ rmean,
        const float* __restrict__ rvar,
        __hip_bfloat16* __restrict__ ah, __hip_bfloat16* __restrict__ al,
        float* __restrict__ scale, float* __restrict__ bias) {
    int g = blockIdx.x * 256 + threadIdx.x;      // 0 .. 294911
    int oc = g / KK;
    int kk = g - oc * KK;
    int kpos = kk >> 7;          // kh*3+kw
    int ic   = kk & 127;
    int j    = ic * 9 + kpos;    // original flat k = ic*9 + kh*3 + kw
    int pidx = (((oc >> 3) * 144 + (j >> 3)) * 8 + (oc & 7)) * 8 + (j & 7);
    double phi = (double)phase[pidx];
    double c   = cos(phi);
    const double a = 0.987, r = 0.99;
    double num = a*a - 2.0*a*r*c + r*r;
    double den = 1.0 - 2.0*a*r*c + (a*r)*(a*r);
    float t = (float)(num / den);
    unsigned short hb = f2bf(t);
    float hf = bf2f(hb);
    ((unsigned short*)ah)[g] = hb;
    ((unsigned short*)al)[g] = f2bf(t - hf);
    if (g < OC) {
        float inv = gamma[g] / sqrtf(rvar[g] + 1e-5f);
        scale[g] = inv;
        bias[g]  = beta[g] - rmean[g] * inv;
    }
}

// ---------------- kernel 2: pad + transpose + bf16 hi/lo split ----------------
__global__ __launch_bounds__(256) void prep_x(
        const float* __restrict__ x,
        __hip_bfloat16* __restrict__ xh, __hip_bfloat16* __restrict__ xl) {
    int hp  = blockIdx.x;    // 0..57
    int img = blockIdx.y;    // 0..63
    __shared__ float tile[IC * 57];   // [ic][w], stride 57
    int t = threadIdx.x;
    bool border = (hp == 0) || (hp == HP - 1);
    if (!border) {
        int h = hp - 1;
        const float* src = x + (long)img * IC * PIX + h * HW;
#pragma unroll
        for (int i = 0; i < 7; ++i) {            // 128*14 float4 = 1792
            int idx = i * 256 + t;
            int ic  = idx / 14;
            int w4  = (idx - ic * 14) * 4;
            float4 v = *(const float4*)&src[(long)ic * PIX + w4];
            tile[ic * 57 + w4 + 0] = v.x;
            tile[ic * 57 + w4 + 1] = v.y;
            tile[ic * 57 + w4 + 2] = v.z;
            tile[ic * 57 + w4 + 3] = v.w;
        }
    }
    __syncthreads();
    long base = ((long)(img * HP + hp)) * HP * IC;
#pragma unroll
    for (int i = 0; i < 4; ++i) {                // 58*16 = 928 vec-tasks
        int v = i * 256 + t;
        if (v < 928) {
            int icg = v & 15;                    // 8 ic per task
            int wp  = v >> 4;                    // 0..57
            bool inw = !border && wp >= 1 && wp <= HW;
            u16x8 hv, lv;
#pragma unroll
            for (int j = 0; j < 8; ++j) {
                float f = inw ? tile[(icg * 8 + j) * 57 + (wp - 1)] : 0.f;
                unsigned short hb = f2bf(f);
                hv[j] = hb;
                lv[j] = f2bf(f - bf2f(hb));
            }
            long o = base + wp * IC + icg * 8;
            *(u16x8*)&((unsigned short*)xh)[o] = hv;
            *(u16x8*)&((unsigned short*)xl)[o] = lv;
        }
    }
}

// ---------------- kernel 3: implicit GEMM conv + BN + ReLU6 ----------------
// 4-phase-per-chunk schedule (m201-style port). Diagnosis R2: READF-then-MFMAS
// bodies serialized LDS and matrix pipes (wall/chunk 3893 ~= 1862 MFMA + 2048
// LDS; allocator collapsed the reg double-buffer at VGPR=100). Fix: split each
// K=32 chunk into 4 phases of 12 MFMA (2x2 acc quadrants); per phase: JIT frag
// reads (8/4/4/0) -> s_barrier -> lgkmcnt(0) -> setprio(1) MFMA setprio(0).
// Staging for chunk k+1 spread 2 DMAs/phase into the other slot; single counted
// vmcnt(2) at P0 (never 0 mid-loop). Single fragment set -> no collapsible
// double-buffer; reads sit adjacent to consumers.
// Slot safety: chunk k's last reads of slot S retire at P2's lgkmcnt(0), which
// precedes P3's s_barrier, which precedes any wave's ISSUE into S (next chunk's
// phases). DMA-landed safety: vmcnt(2)+s_barrier at P0 before first read of S.
__global__ __launch_bounds__(256, 2) void conv_gemm(
        const __hip_bfloat16* __restrict__ ah, const __hip_bfloat16* __restrict__ al,
        const __hip_bfloat16* __restrict__ xh, const __hip_bfloat16* __restrict__ xl,
        const float* __restrict__ scale, const float* __restrict__ bias,
        float* __restrict__ out) {
    __shared__ __hip_bfloat16 sAh[2][4096], sAl[2][4096];
    __shared__ __hip_bfloat16 sBh[2][4096], sBl[2][4096];   // 64 KB total

    // XCD-aware swizzle: consecutive blockIdx -> XCD round-robin (b&7).
    int b   = blockIdx.x;
    int xcd = b & 7;
    int idx = b >> 3;            // 0..399 per XCD
    int img = xcd * 8 + idx / 50;
    int rem = idx % 50;
    int mt  = rem >> 1;          // 0..24  pixel tile
    int ot  = rem & 1;           // oc tile

    int t    = threadIdx.x;
    int lane = t & 63;
    int wave = t >> 6;
    int wm   = wave & 1;     // oc half (64)
    int wn   = wave >> 1;    // pixel half (64)

    int row0 = t >> 2;
    int col0 = (((t & 3) ^ ((t >> 3) & 3))) << 3;

    const __hip_bfloat16* pah0 = ah + (long)(ot * 128 + row0) * KK + col0;
    const __hip_bfloat16* pah1 = pah0 + (long)64 * KK;
    const __hip_bfloat16* pal0 = al + (long)(ot * 128 + row0) * KK + col0;
    const __hip_bfloat16* pal1 = pal0 + (long)64 * KK;

    int m0 = mt * 128 + row0;      if (m0 > PIX - 1) m0 = PIX - 1;
    int m1 = mt * 128 + row0 + 64; if (m1 > PIX - 1) m1 = PIX - 1;
    int h0 = m0 / HW, w0 = m0 - h0 * HW;
    int h1 = m1 / HW, w1 = m1 - h1 * HW;
    const __hip_bfloat16* pxh0 = xh + (long)((img * HP + h0) * HP + w0) * IC + col0;
    const __hip_bfloat16* pxh1 = xh + (long)((img * HP + h1) * HP + w1) * IC + col0;
    const __hip_bfloat16* pxl0 = xl + (long)((img * HP + h0) * HP + w0) * IC + col0;
    const __hip_bfloat16* pxl1 = xl + (long)((img * HP + h1) * HP + w1) * IC + col0;

    int ar[4], br[4];
#pragma unroll
    for (int f = 0; f < 4; ++f) {
        ar[f] = lds_off(wm * 64 + f * 16 + (lane & 15), lane >> 4);
        br[f] = lds_off(wn * 64 + f * 16 + (lane & 15), lane >> 4);
    }

    f32x4 acc[4][4];
#pragma unroll
    for (int i = 0; i < 4; ++i)
#pragma unroll
        for (int jj = 0; jj < 4; ++jj) acc[i][jj] = (f32x4){0.f, 0.f, 0.f, 0.f};

    bf16x8 aH[4], aL[4], bH[4], bL[4];   // single fragment set

// stage pair P of chunk ci into slot S (2 wave-DMAs per pair, 4 pairs = chunk)
#define ISSUE_PAIR(ci, S, P)                                                   \
    {                                                                          \
        int _c = (ci);                                                         \
        int bs = 32 * _c + (_c >= 12 ? 7040 : 0) + (_c >= 24 ? 7040 : 0);      \
        long a0 = (long)_c * 32;                                               \
        if ((P) == 0) { async_load16(pah0 + a0, &sAh[S][t * 8]);               \
                        async_load16(pah1 + a0, &sAh[S][2048 + t * 8]); }      \
        if ((P) == 1) { async_load16(pal0 + a0, &sAl[S][t * 8]);               \
                        async_load16(pal1 + a0, &sAl[S][2048 + t * 8]); }      \
        if ((P) == 2) { async_load16(pxh0 + bs, &sBh[S][t * 8]);               \
                        async_load16(pxh1 + bs, &sBh[S][2048 + t * 8]); }      \
        if ((P) == 3) { async_load16(pxl0 + bs, &sBl[S][t * 8]);               \
                        async_load16(pxl1 + bs, &sBl[S][2048 + t * 8]); }      \
    }

#define READ2A(S, f) { aH[f] = *(const bf16x8*)&sAh[S][ar[f]];                 \
                       aL[f] = *(const bf16x8*)&sAl[S][ar[f]]; }
#define READ2B(S, f) { bH[f] = *(const bf16x8*)&sBh[S][br[f]];                 \
                       bL[f] = *(const bf16x8*)&sBl[S][br[f]]; }

#define MFMA1(fm, fn)                                                          \
    acc[fm][fn] = __builtin_amdgcn_mfma_f32_16x16x32_bf16(aL[fm], bH[fn], acc[fm][fn], 0, 0, 0); \
    acc[fm][fn] = __builtin_amdgcn_mfma_f32_16x16x32_bf16(aH[fm], bL[fn], acc[fm][fn], 0, 0, 0); \
    acc[fm][fn] = __builtin_amdgcn_mfma_f32_16x16x32_bf16(aH[fm], bH[fn], acc[fm][fn], 0, 0, 0);

#define MFMA_G(f0, f1, n0, n1)                                                 \
    { MFMA1(f0, n0) MFMA1(f0, n1) MFMA1(f1, n0) MFMA1(f1, n1) }

#define SBAR  __builtin_amdgcn_s_barrier(); __builtin_amdgcn_sched_barrier(0);
#define LGKM0 asm volatile("s_waitcnt lgkmcnt(0)" ::: "memory");               \
              __builtin_amdgcn_sched_barrier(0);

// one K=32 chunk: slot S holds chunk k; stage chunk k+1 into slot NS.
#define CHUNK(k, S, NS, STAGE, VMC)                                            \
    /* P0: quadrant (fm01,fn01); sync chunk-k DMAs */                          \
    if (STAGE) ISSUE_PAIR((k) + 1, NS, 0);                                     \
    asm volatile("s_waitcnt vmcnt(" #VMC ")" ::: "memory");                    \
    SBAR                                                                       \
    READ2A(S, 0) READ2A(S, 1) READ2B(S, 0) READ2B(S, 1)                        \
    LGKM0                                                                      \
    __builtin_amdgcn_s_setprio(1);                                             \
    MFMA_G(0, 1, 0, 1)                                                         \
    __builtin_amdgcn_s_setprio(0);                                             \
    /* P1: quadrant (fm01,fn23) */                                             \
    READ2B(S, 2) READ2B(S, 3)                                                  \
    if (STAGE) ISSUE_PAIR((k) + 1, NS, 1);                                     \
    __builtin_amdgcn_sched_barrier(0);                                         \
    SBAR                                                                       \
    LGKM0                                                                      \
    __builtin_amdgcn_s_setprio(1);                                             \
    MFMA_G(0, 1, 2, 3)                                                         \
    __builtin_amdgcn_s_setprio(0);                                             \
    /* P2: quadrant (fm23,fn01) */                                             \
    READ2A(S, 2) READ2A(S, 3)                                                  \
    if (STAGE) ISSUE_PAIR((k) + 1, NS, 2);                                     \
    __builtin_amdgcn_sched_barrier(0);                                         \
    SBAR                                                                       \
    LGKM0                                                                      \
    __builtin_amdgcn_s_setprio(1);                                             \
    MFMA_G(2, 3, 0, 1)                                                         \
    __builtin_amdgcn_s_setprio(0);                                             \
    /* P3: quadrant (fm23,fn23); no new frags */                               \
    if (STAGE) ISSUE_PAIR((k) + 1, NS, 3);                                     \
    __builtin_amdgcn_sched_barrier(0);                                         \
    SBAR                                                                       \
    __builtin_amdgcn_s_setprio(1);                                             \
    MFMA_G(2, 3, 2, 3)                                                         \
    __builtin_amdgcn_s_setprio(0);

    // prologue: stage all of chunk 0 into slot 0
    ISSUE_PAIR(0, 0, 0) ISSUE_PAIR(0, 0, 1) ISSUE_PAIR(0, 0, 2) ISSUE_PAIR(0, 0, 3)

#pragma unroll 1
    for (int it = 0; it < 17; ++it) {        // chunks 0..33
        int k = it * 2;
        CHUNK(k,     0, 1, 1, 2)
        CHUNK(k + 1, 1, 0, 1, 2)
    }
    CHUNK(34, 0, 1, 1, 2)                    // stages chunk 35
    CHUNK(35, 1, 0, 0, 0)                    // final: no staging, full drain

#undef ISSUE_PAIR
#undef READ2A
#undef READ2B
#undef MFMA1
#undef MFMA_G
#undef SBAR
#undef LGKM0
#undef CHUNK

    // epilogue: BN (eval) + ReLU6, store fp32
    int pixc = mt * 128 + wn * 64 + (lane & 15);
    int occ0 = ot * 128 + wm * 64 + ((lane >> 4) << 2);
#pragma unroll
    for (int fm = 0; fm < 4; ++fm) {
#pragma unroll
        for (int r = 0; r < 4; ++r) {
            int oc = occ0 + fm * 16 + r;
            float sc = scale[oc], bi = bias[oc];
            long obase = ((long)(img * OC + oc)) * PIX;
#pragma unroll
            for (int fn = 0; fn < 4; ++fn) {
                int pix = pixc + fn * 16;
                if (pix < PIX) {
                    float v = acc[fm][fn][r] * sc + bi;
                    v = fminf(fmaxf(v, 0.f), 6.f);
                    out[obase + pix] = v;
                }
            }
        }
    }
}

// ---------------- launch ----------------
extern "C" void kernel_launch(void* const* d_in, const int* in_sizes, int n_in,
                              void* d_out, int out_size, void* d_ws, size_t ws_size,
                              hipStream_t stream) {
    const float* x     = (const float*)d_in[0];
    const float* phase = (const float*)d_in[1];
    const float* gamma = (const float*)d_in[2];
    const float* beta  = (const float*)d_in[3];
    const float* rmean = (const float*)d_in[4];
    const float* rvar  = (const float*)d_in[5];
    float* out = (float*)d_out;

    __hip_bfloat16* xh = (__hip_bfloat16*)d_ws;
    __hip_bfloat16* xl = xh + XPAD_ELEMS;
    __hip_bfloat16* ah = xl + XPAD_ELEMS;
    __hip_bfloat16* al = ah + A_ELEMS;
    float* scale = (float*)(al + A_ELEMS);
    float* bias  = scale + OC;

    prep_weights<<<A_ELEMS / 256, 256, 0, stream>>>(phase, gamma, beta, rmean, rvar,
                                                    ah, al, scale, bias);
    prep_x<<<dim3(HP, NB), 256, 0, stream>>>(x, xh, xl);
    conv_gemm<<<NB * 50, 256, 0, stream>>>(ah, al, xh, xl, scale, bias, out);
}